// Round 7
// baseline (1233.753 us; speedup 1.0000x reference)
//
#include <hip/hip_runtime.h>

// NTM controller B=64,T=512,I=64,H=256,O=64. Memory module provably dead
// (mem0=0 -> lw=0 -> add=tanh(0)=0 -> mem stays 0, read_vec=0):
//   LSTM recurrence + out = h @ W_dec[:, :256]^T + b_dec.
//
// Capacity law (rounds 1-5): W_hh fp16 = 512 KB/CU must be register+LDS resident.
// Only 16 waves x 128 VGPR = 512 KB of arch regs fits it (1024-thread block; the
// 1024-size workgroup itself forces the <=128 VGPR budget -- no occupancy attrs).
//   thread = (unit g = tid>>2, k-window m = tid&3); owns gate rows {g,256+g,512+g,768+g}
//   restricted to k in [64m,64m+64): 23 f16x2 pairs/row in regs (92 VGPRs),
//   9 pairs/row in LDS ([9][1024] uint4, 144 KB, 16B/lane contiguous reads).
//   k-reduction: shfl_xor butterfly over the 4-lane group; x-projection added
//   AFTER the butterfly (round-6 bug: adding it per-lane pre-reduction counted
//   it 4x). One barrier/step; h double-buffered in LDS.
// Phase 1 (xproj): XPh[b][t][g][4] f16 = x@W_ih^T + b_ih + b_hh (i,f,g,o per unit).
// Phase 3 (dec):   out[b,t,:] = H[b,t,:] @ W_dec[:, :256]^T + b_dec.

typedef _Float16 f16x2 __attribute__((ext_vector_type(2)));

#define NB   64
#define TT   512
#define PREG 23          // reg-resident pairs per row (k-slices 2*PREG)
#define PLDS 9           // LDS-resident pairs per row
#define XP_BYTES  (67108864u)   // 64*512*1024*2
#define HD_BYTES  (16777216u)   // 64*512*256*2

__device__ unsigned char g_ntm_ws[XP_BYTES + HD_BYTES];  // fallback workspace

union U32H { unsigned int u; f16x2 h; };
union USH  { _Float16 f; unsigned short u; };
static __device__ __forceinline__ unsigned int pack2f(float a, float b) {
    U32H v; v.h = f16x2{(_Float16)a, (_Float16)b}; return v.u;
}
static __device__ __forceinline__ f16x2 up(unsigned int u) { U32H v; v.u = u; return v.h; }
static __device__ __forceinline__ unsigned short f2s(float a) { USH v; v.f = (_Float16)a; return v.u; }

__device__ __forceinline__ float sigf(float x) { return 1.0f / (1.0f + __expf(-x)); }
__device__ __forceinline__ float tanhfast(float x) {
    float e = __expf(2.0f * x);
    return 1.0f - 2.0f / (e + 1.0f);
}

#if __has_builtin(__builtin_amdgcn_fdot2)
__device__ __forceinline__ float dot2(f16x2 a, f16x2 b, float c) {
    return __builtin_amdgcn_fdot2(a, b, c, false);
}
#else
__device__ __forceinline__ float dot2(f16x2 a, f16x2 b, float c) {
    return c + (float)a.x * (float)b.x + (float)a.y * (float)b.y;
}
#endif

// ---------------- phase 1: x-projection ----------------
// XPh[b][t][unit g][r] f16, r=0:i,1:f,2:g,3:o. Thread tid handles rows tid, tid+512.
__global__ void __attribute__((amdgpu_flat_work_group_size(512, 512)))
xproj_kernel(const float* __restrict__ x_seq, const float* __restrict__ W_ih,
             const float* __restrict__ b_ih, const float* __restrict__ b_hh,
             unsigned short* XPh)
{
    if (!XPh) XPh = (unsigned short*)g_ntm_ws;
    __shared__ unsigned int xq[128 * 32];     // 16 KB: 128 t-rows of x, f16 pairs
    const int tid = threadIdx.x;
    const int b   = blockIdx.x >> 2;
    const int q   = blockIdx.x & 3;

    {   // stage x chunk
        const float* src = x_seq + ((size_t)b * TT + (size_t)q * 128 + (tid >> 2)) * 64
                         + (tid & 3) * 16;
        unsigned int* dst = xq + (tid >> 2) * 32 + (tid & 3) * 8;
#pragma unroll
        for (int i = 0; i < 4; ++i) {
            float4 v = ((const float4*)src)[i];
            dst[2 * i]     = pack2f(v.x, v.y);
            dst[2 * i + 1] = pack2f(v.z, v.w);
        }
    }

    unsigned int w0p[32], w1p[32];            // rows tid, tid+512 as f16 pairs
    {
        const float* r0 = W_ih + (size_t)tid * 64;
        const float* r1 = W_ih + (size_t)(tid + 512) * 64;
#pragma unroll
        for (int i = 0; i < 16; ++i) {
            float4 v0 = *(const float4*)(r0 + 4 * i);
            float4 v1 = *(const float4*)(r1 + 4 * i);
            w0p[2*i] = pack2f(v0.x, v0.y); w0p[2*i+1] = pack2f(v0.z, v0.w);
            w1p[2*i] = pack2f(v1.x, v1.y); w1p[2*i+1] = pack2f(v1.z, v1.w);
        }
    }
    const float bias0 = b_ih[tid]       + b_hh[tid];
    const float bias1 = b_ih[tid + 512] + b_hh[tid + 512];
    const int   g4A   = (tid & 255) * 4 + ((tid < 256) ? 0 : 1);   // row tid -> gate i or f
    __syncthreads();

    unsigned short* outh = XPh + ((size_t)b * TT + (size_t)q * 128) * 1024;
    for (int tt = 0; tt < 128; ++tt) {
        const uint4* xr = (const uint4*)(xq + tt * 32);
        float a0 = bias0, a1 = bias1;
        float a2 = 0.f, a3 = 0.f, a4 = 0.f, a5 = 0.f, a6 = 0.f, a7 = 0.f;
#pragma unroll
        for (int i = 0; i < 8; ++i) {
            uint4 xv = xr[i];
            a0 = dot2(up(w0p[4*i]),   up(xv.x), a0);  a1 = dot2(up(w1p[4*i]),   up(xv.x), a1);
            a2 = dot2(up(w0p[4*i+1]), up(xv.y), a2);  a3 = dot2(up(w1p[4*i+1]), up(xv.y), a3);
            a4 = dot2(up(w0p[4*i+2]), up(xv.z), a4);  a5 = dot2(up(w1p[4*i+2]), up(xv.z), a5);
            a6 = dot2(up(w0p[4*i+3]), up(xv.w), a6);  a7 = dot2(up(w1p[4*i+3]), up(xv.w), a7);
        }
        const float gA = (a0 + a2) + (a4 + a6);   // row tid
        const float gB = (a1 + a3) + (a5 + a7);   // row tid+512
        outh[tt * 1024 + g4A]     = f2s(gA);
        outh[tt * 1024 + g4A + 2] = f2s(gB);      // row tid+512 = gate r+2 of same unit
    }
}

// ---------------- phase 2: recurrence ----------------
// LDS: whhl uint4[9][1024] (147456 B) | h16 _Float16[2][256] (1024 B)
__global__ void __attribute__((amdgpu_flat_work_group_size(1024, 1024)))
ntm_rec(const float* __restrict__ W_hh,
        const unsigned short* __restrict__ XPh_in,
        unsigned short* __restrict__ Hd_in)
{
    extern __shared__ char smem[];
    uint4*    whhl = (uint4*)smem;                               // [9][1024]
    _Float16* h16  = (_Float16*)(smem + PLDS * 1024 * 16);       // [2][256]

    const unsigned short* XPh = XPh_in ? XPh_in : (const unsigned short*)g_ntm_ws;
    unsigned short*       Hd  = Hd_in  ? Hd_in  : (unsigned short*)(g_ntm_ws + XP_BYTES);

    const int tid = threadIdx.x;
    const int b   = blockIdx.x;
    const int g   = tid >> 2;        // hidden unit
    const int m   = tid & 3;         // k-window index

    // ---- load weights: 4 gate rows of unit g, k in [64m, 64m+64) ----
    f16x2 wr[4][PREG];
#pragma unroll
    for (int r = 0; r < 4; ++r) {
        const float* row = W_hh + ((size_t)(r * 256 + g)) * 256 + m * 64;
#pragma unroll
        for (int pp = 0; pp < 32; ++pp) {
            float2 v = *(const float2*)(row + 2 * pp);
            if (pp < PREG) {
                wr[r][pp] = f16x2{(_Float16)v.x, (_Float16)v.y};
            } else {
                ((unsigned int*)&whhl[(pp - PREG) * 1024 + tid])[r] = pack2f(v.x, v.y);
            }
        }
    }
    if (tid < 64) ((uint4*)h16)[tid] = make_uint4(0u, 0u, 0u, 0u);   // both h buffers = 0
    float c_state = 0.f;
    __syncthreads();

    const uint2* xpb = (const uint2*)XPh + (size_t)b * TT * 256;     // [t][unit] (i,f | g,o)
    uint4*       Hd4 = (uint4*)Hd + (size_t)b * TT * 32;             // [t][32]

    uint2 xpc = xpb[g];                                              // t = 0

    for (int t = 0; t < TT; ++t) {
        const uint4* hq = (const uint4*)(h16 + (t & 1) * 256) + 8 * m;
        uint2 xpn = xpc;
        if (t + 1 < TT) xpn = xpb[(size_t)(t + 1) * 256 + g];        // prefetch

        float a0 = 0.f, a1 = 0.f, a2 = 0.f, a3 = 0.f;
#pragma unroll
        for (int i = 0; i < 8; ++i) {
            const uint4 hv = hq[i];
#pragma unroll
            for (int j = 0; j < 4; ++j) {
                const int pp = 4 * i + j;
                const f16x2 hp = up(j == 0 ? hv.x : j == 1 ? hv.y : j == 2 ? hv.z : hv.w);
                if (pp < PREG) {
                    a0 = dot2(wr[0][pp], hp, a0);
                    a1 = dot2(wr[1][pp], hp, a1);
                    a2 = dot2(wr[2][pp], hp, a2);
                    a3 = dot2(wr[3][pp], hp, a3);
                } else {
                    const uint4 wv = whhl[(pp - PREG) * 1024 + tid];
                    a0 = dot2(up(wv.x), hp, a0);
                    a1 = dot2(up(wv.y), hp, a1);
                    a2 = dot2(up(wv.z), hp, a2);
                    a3 = dot2(up(wv.w), hp, a3);
                }
            }
        }
        // butterfly sum over the 4-lane group (k-windows) -> all 4 lanes hold full W_hh.h
        a0 += __shfl_xor(a0, 1); a1 += __shfl_xor(a1, 1);
        a2 += __shfl_xor(a2, 1); a3 += __shfl_xor(a3, 1);
        a0 += __shfl_xor(a0, 2); a1 += __shfl_xor(a1, 2);
        a2 += __shfl_xor(a2, 2); a3 += __shfl_xor(a3, 2);
        // add x-projection (+biases) ONCE, after the reduction (round-6 bug: pre-
        // reduction per-lane add counted it 4x). All lanes add the same value ->
        // lane-consistent gates.
        {
            const f16x2 lo = up(xpc.x), hi = up(xpc.y);
            a0 += (float)lo.x; a1 += (float)lo.y; a2 += (float)hi.x; a3 += (float)hi.y;
        }
        // LSTM cell (redundant in all 4 lanes; deterministic)
        c_state = sigf(a1) * c_state + sigf(a0) * tanhfast(a2);
        const float hn = sigf(a3) * tanhfast(c_state);

        _Float16* hw = h16 + ((t + 1) & 1) * 256;
        if (m == 0) hw[g] = (_Float16)hn;
        __syncthreads();                                             // h_t published
        if (tid < 32) Hd4[(size_t)t * 32 + tid] = ((const uint4*)hw)[tid];
        xpc = xpn;
    }
}

// ---------------- phase 3: decode ----------------
// out[b,t,o] = b_dec[o] + H[b,t,:256] . W_dec[o,:256]
__global__ void __attribute__((amdgpu_flat_work_group_size(256, 256)))
dec_kernel(const unsigned short* __restrict__ Hd_in,
           const float* __restrict__ W_dec, const float* __restrict__ b_dec,
           float* __restrict__ out)
{
    const unsigned short* Hd = Hd_in ? Hd_in : (const unsigned short*)(g_ntm_ws + XP_BYTES);
    __shared__ unsigned int wdl[64 * 132];    // W_dec pairs, padded stride 132
    __shared__ uint4 ht[32 * 32];             // 32 t-rows x 256 f16

    const int tid = threadIdx.x;
    const int b = blockIdx.x >> 2, q = blockIdx.x & 3;

    for (int idx = tid; idx < 64 * 128; idx += 256) {
        const int o = idx >> 7, pp = idx & 127;
        wdl[o * 132 + pp] = pack2f(W_dec[(size_t)o * 384 + 2 * pp],
                                   W_dec[(size_t)o * 384 + 2 * pp + 1]);
    }
    const int o = tid & 63, tq = tid >> 6;
    const float bd = b_dec[o];
    const uint4* Hdb  = (const uint4*)Hd + ((size_t)b * TT + (size_t)q * 128) * 32;
    float*       outb = out + ((size_t)b * TT + (size_t)q * 128) * 64;

    for (int s = 0; s < 4; ++s) {
        __syncthreads();
#pragma unroll
        for (int i = 0; i < 4; ++i) {
            const int idx = tid + 256 * i;                 // 1024 uint4 = 32 rows
            ht[idx] = Hdb[s * 1024 + idx];
        }
        __syncthreads();

        float acc[8];
#pragma unroll
        for (int j = 0; j < 8; ++j) acc[j] = 0.f;

#pragma unroll
        for (int c = 0; c < 8; ++c) {                      // k-chunks of 32 slices
            uint4 w0, w1, w2, w3;
            {
                const unsigned int* wp = wdl + o * 132 + 16 * c;
                w0 = make_uint4(wp[0],  wp[1],  wp[2],  wp[3]);
                w1 = make_uint4(wp[4],  wp[5],  wp[6],  wp[7]);
                w2 = make_uint4(wp[8],  wp[9],  wp[10], wp[11]);
                w3 = make_uint4(wp[12], wp[13], wp[14], wp[15]);
            }
#pragma unroll
            for (int j = 0; j < 8; ++j) {
                const uint4* hr = &ht[(tq * 8 + j) * 32 + 4 * c];
                const uint4 h0 = hr[0], h1 = hr[1], h2 = hr[2], h3 = hr[3];
                float d = acc[j];
                d = dot2(up(w0.x), up(h0.x), d); d = dot2(up(w0.y), up(h0.y), d);
                d = dot2(up(w0.z), up(h0.z), d); d = dot2(up(w0.w), up(h0.w), d);
                d = dot2(up(w1.x), up(h1.x), d); d = dot2(up(w1.y), up(h1.y), d);
                d = dot2(up(w1.z), up(h1.z), d); d = dot2(up(w1.w), up(h1.w), d);
                d = dot2(up(w2.x), up(h2.x), d); d = dot2(up(w2.y), up(h2.y), d);
                d = dot2(up(w2.z), up(h2.z), d); d = dot2(up(w2.w), up(h2.w), d);
                d = dot2(up(w3.x), up(h3.x), d); d = dot2(up(w3.y), up(h3.y), d);
                d = dot2(up(w3.z), up(h3.z), d); d = dot2(up(w3.w), up(h3.w), d);
                acc[j] = d;
            }
        }
#pragma unroll
        for (int j = 0; j < 8; ++j)
            outb[(size_t)(s * 32 + tq * 8 + j) * 64 + o] = acc[j] + bd;
    }
}

extern "C" void kernel_launch(void* const* d_in, const int* in_sizes, int n_in,
                              void* d_out, int out_size, void* d_ws, size_t ws_size,
                              hipStream_t stream) {
    const float* x_seq = (const float*)d_in[0];
    const float* W_ih  = (const float*)d_in[1];
    const float* W_hh  = (const float*)d_in[2];
    const float* b_ih  = (const float*)d_in[3];
    const float* b_hh  = (const float*)d_in[4];
    // d_in[5..8] unused: mem == 0 forever
    const float* W_dec = (const float*)d_in[9];
    const float* b_dec = (const float*)d_in[10];
    float* out = (float*)d_out;

    unsigned short* XPh = nullptr;   // null -> kernels fall back to g_ntm_ws
    unsigned short* Hd  = nullptr;
    if (ws_size >= (size_t)XP_BYTES + HD_BYTES) {
        XPh = (unsigned short*)d_ws;
        Hd  = (unsigned short*)((unsigned char*)d_ws + XP_BYTES);
    }

    hipLaunchKernelGGL(xproj_kernel, dim3(256), dim3(512), 0, stream,
                       x_seq, W_ih, b_ih, b_hh, XPh);

    const size_t smem_rec = (size_t)PLDS * 1024 * 16 + 1024;   // 148480 B
    hipFuncSetAttribute((const void*)&ntm_rec,
                        hipFuncAttributeMaxDynamicSharedMemorySize, (int)smem_rec);
    hipLaunchKernelGGL(ntm_rec, dim3(NB), dim3(1024), smem_rec, stream,
                       W_hh, XPh, Hd);

    hipLaunchKernelGGL(dec_kernel, dim3(256), dim3(256), 0, stream,
                       Hd, W_dec, b_dec, out);
}

// Round 8
// 947.246 us; speedup vs baseline: 1.3025x; 1.3025x over previous
//
#include <hip/hip_runtime.h>

// NTM controller B=64,T=512,I=64,H=256,O=64. Memory module provably dead
// (mem0=0 -> lw=0 -> add=tanh(0)=0 -> mem stays 0, read_vec=0):
//   LSTM recurrence + out = h @ W_dec[:, :256]^T + b_dec.
//
// Allocator law (rounds 1-7): default arch-VGPR target = 65536/blockDim
// (512thr->128, 1024thr->64, 256thr->256); launch_bounds / waves_per_eu don't
// raise it. W_hh fp16 (512 KB) needs ~360 KB register-resident => request regs
// explicitly: amdgpu_num_vgpr(240) @ 512 threads (2 waves/SIMD x 240 = 480 <= 512).
//
// rec: 64 blocks x 512 thr. Thread (u=tid>>1, e=tid&1) owns rows
// {u+512e, 256+u+512e}: e=0 -> (i_u,f_u), e=1 -> (g_u,o_u). Full k=256 per row:
// 100 f16x2 pairs/row in VGPRs (200 regs), 28 pairs/row in LDS [14][512] uint4
// (114688 B, 16 B/lane contiguous = conflict-free). Gate exchange = 2x shfl_xor
// with lane^1 (same wave). One barrier/step, h f16 double-buffered in LDS.
// Phase 1 (xproj): XPh[b][t][unit][4] f16 = x@W_ih^T + b_ih + b_hh (i,f,g,o).
// Phase 3 (dec):   out[b,t,:] = H[b,t,:] @ W_dec[:, :256]^T + b_dec.

typedef _Float16 f16x2 __attribute__((ext_vector_type(2)));

#define NB   64
#define TT   512
#define RPP  100         // reg-resident pairs per row
#define QRG  25          // reg h-quads (4 pairs each): 25*4 = 100
#define QLD  7           // LDS h-quads: 7*4 = 28 pairs per row
#define XP_BYTES  (67108864u)   // 64*512*1024*2
#define HD_BYTES  (16777216u)   // 64*512*256*2

__device__ unsigned char g_ntm_ws[XP_BYTES + HD_BYTES];  // fallback workspace

union U32H { unsigned int u; f16x2 h; };
union USH  { _Float16 f; unsigned short u; };
static __device__ __forceinline__ unsigned int pack2f(float a, float b) {
    U32H v; v.h = f16x2{(_Float16)a, (_Float16)b}; return v.u;
}
static __device__ __forceinline__ f16x2 up(unsigned int u) { U32H v; v.u = u; return v.h; }
static __device__ __forceinline__ unsigned short f2s(float a) { USH v; v.f = (_Float16)a; return v.u; }

__device__ __forceinline__ float sigf(float x) { return 1.0f / (1.0f + __expf(-x)); }
__device__ __forceinline__ float tanhfast(float x) {
    float e = __expf(2.0f * x);
    return 1.0f - 2.0f / (e + 1.0f);
}

#if __has_builtin(__builtin_amdgcn_fdot2)
__device__ __forceinline__ float dot2(f16x2 a, f16x2 b, float c) {
    return __builtin_amdgcn_fdot2(a, b, c, false);
}
#else
__device__ __forceinline__ float dot2(f16x2 a, f16x2 b, float c) {
    return c + (float)a.x * (float)b.x + (float)a.y * (float)b.y;
}
#endif

// ---------------- phase 1: x-projection ----------------
// XPh[b][t][unit g][r] f16, r=0:i,1:f,2:g,3:o. Thread tid handles rows tid, tid+512.
__global__ void __attribute__((amdgpu_flat_work_group_size(512, 512)))
xproj_kernel(const float* __restrict__ x_seq, const float* __restrict__ W_ih,
             const float* __restrict__ b_ih, const float* __restrict__ b_hh,
             unsigned short* XPh)
{
    if (!XPh) XPh = (unsigned short*)g_ntm_ws;
    __shared__ unsigned int xq[128 * 32];     // 16 KB: 128 t-rows of x, f16 pairs
    const int tid = threadIdx.x;
    const int b   = blockIdx.x >> 2;
    const int q   = blockIdx.x & 3;

    {   // stage x chunk
        const float* src = x_seq + ((size_t)b * TT + (size_t)q * 128 + (tid >> 2)) * 64
                         + (tid & 3) * 16;
        unsigned int* dst = xq + (tid >> 2) * 32 + (tid & 3) * 8;
#pragma unroll
        for (int i = 0; i < 4; ++i) {
            float4 v = ((const float4*)src)[i];
            dst[2 * i]     = pack2f(v.x, v.y);
            dst[2 * i + 1] = pack2f(v.z, v.w);
        }
    }

    unsigned int w0p[32], w1p[32];            // rows tid, tid+512 as f16 pairs
    {
        const float* r0 = W_ih + (size_t)tid * 64;
        const float* r1 = W_ih + (size_t)(tid + 512) * 64;
#pragma unroll
        for (int i = 0; i < 16; ++i) {
            float4 v0 = *(const float4*)(r0 + 4 * i);
            float4 v1 = *(const float4*)(r1 + 4 * i);
            w0p[2*i] = pack2f(v0.x, v0.y); w0p[2*i+1] = pack2f(v0.z, v0.w);
            w1p[2*i] = pack2f(v1.x, v1.y); w1p[2*i+1] = pack2f(v1.z, v1.w);
        }
    }
    const float bias0 = b_ih[tid]       + b_hh[tid];
    const float bias1 = b_ih[tid + 512] + b_hh[tid + 512];
    const int   g4A   = (tid & 255) * 4 + ((tid < 256) ? 0 : 1);   // row tid -> gate i or f
    __syncthreads();

    unsigned short* outh = XPh + ((size_t)b * TT + (size_t)q * 128) * 1024;
    for (int tt = 0; tt < 128; ++tt) {
        const uint4* xr = (const uint4*)(xq + tt * 32);
        float a0 = bias0, a1 = bias1;
        float a2 = 0.f, a3 = 0.f, a4 = 0.f, a5 = 0.f, a6 = 0.f, a7 = 0.f;
#pragma unroll
        for (int i = 0; i < 8; ++i) {
            uint4 xv = xr[i];
            a0 = dot2(up(w0p[4*i]),   up(xv.x), a0);  a1 = dot2(up(w1p[4*i]),   up(xv.x), a1);
            a2 = dot2(up(w0p[4*i+1]), up(xv.y), a2);  a3 = dot2(up(w1p[4*i+1]), up(xv.y), a3);
            a4 = dot2(up(w0p[4*i+2]), up(xv.z), a4);  a5 = dot2(up(w1p[4*i+2]), up(xv.z), a5);
            a6 = dot2(up(w0p[4*i+3]), up(xv.w), a6);  a7 = dot2(up(w1p[4*i+3]), up(xv.w), a7);
        }
        const float gA = (a0 + a2) + (a4 + a6);   // row tid
        const float gB = (a1 + a3) + (a5 + a7);   // row tid+512
        outh[tt * 1024 + g4A]     = f2s(gA);
        outh[tt * 1024 + g4A + 2] = f2s(gB);      // row tid+512 = gate r+2 of same unit
    }
}

// ---------------- phase 2: recurrence ----------------
// LDS: wl4 uint4[14][512] (114688 B) | h16 _Float16[2][256] (1024 B)
__global__ void
__attribute__((amdgpu_flat_work_group_size(512, 512), amdgpu_waves_per_eu(2, 2),
               amdgpu_num_vgpr(240)))
ntm_rec(const float* __restrict__ W_hh,
        const unsigned short* __restrict__ XPh_in,
        unsigned short* __restrict__ Hd_in)
{
    extern __shared__ char smem[];
    uint4*    wl4 = (uint4*)smem;                         // [14][512]
    _Float16* h16 = (_Float16*)(smem + 14 * 512 * 16);    // [2][256]

    const unsigned short* XPh = XPh_in ? XPh_in : (const unsigned short*)g_ntm_ws;
    unsigned short*       Hd  = Hd_in  ? Hd_in  : (unsigned short*)(g_ntm_ws + XP_BYTES);

    const int tid = threadIdx.x;
    const int b   = blockIdx.x;
    const int u   = tid >> 1;        // hidden unit
    const int e   = tid & 1;         // 0: rows (i_u, f_u); 1: rows (g_u, o_u)

    // ---- weights: rows u+512e (gate 2e) and 256+u+512e (gate 2e+1), full k ----
    const float* r0 = W_hh + (size_t)(u + 512 * e) * 256;
    const float* r1 = W_hh + (size_t)(256 + u + 512 * e) * 256;

    f16x2 w0[RPP], w1[RPP];
#pragma unroll
    for (int p = 0; p < RPP; ++p) {
        float2 va = *(const float2*)(r0 + 2 * p);
        float2 vb = *(const float2*)(r1 + 2 * p);
        w0[p] = f16x2{(_Float16)va.x, (_Float16)va.y};
        w1[p] = f16x2{(_Float16)vb.x, (_Float16)vb.y};
    }
#pragma unroll
    for (int qq = 0; qq < QLD; ++qq) {        // pairs RPP+4qq .. RPP+4qq+3
        const float* s0 = r0 + 2 * (RPP + 4 * qq);
        const float* s1 = r1 + 2 * (RPP + 4 * qq);
        wl4[(2 * qq)     * 512 + tid] = make_uint4(pack2f(s0[0], s0[1]), pack2f(s0[2], s0[3]),
                                                   pack2f(s0[4], s0[5]), pack2f(s0[6], s0[7]));
        wl4[(2 * qq + 1) * 512 + tid] = make_uint4(pack2f(s1[0], s1[1]), pack2f(s1[2], s1[3]),
                                                   pack2f(s1[4], s1[5]), pack2f(s1[6], s1[7]));
    }
    if (tid < 64) ((uint4*)h16)[tid] = make_uint4(0u, 0u, 0u, 0u);   // both h buffers = 0
    float c_state = 0.f;
    __syncthreads();

    const unsigned int* xpb = (const unsigned int*)XPh + (size_t)b * TT * 512;
    uint4*              Hd4 = (uint4*)Hd + (size_t)b * TT * 32;

    unsigned int xpc = xpb[tid];                                     // t = 0

    for (int t = 0; t < TT; ++t) {
        const uint4* hq = (const uint4*)(h16 + (t & 1) * 256);
        unsigned int xpn = xpc;
        if (t + 1 < TT) xpn = xpb[(size_t)(t + 1) * 512 + tid];      // prefetch

        float a0 = 0.f, a1 = 0.f, a2 = 0.f, a3 = 0.f;
        // ---- register-resident pairs 0..99 ----
#pragma unroll
        for (int q = 0; q < QRG; ++q) {
            const uint4 hv = hq[q];
            a0 = dot2(w0[4*q],   up(hv.x), a0);  a2 = dot2(w1[4*q],   up(hv.x), a2);
            a1 = dot2(w0[4*q+1], up(hv.y), a1);  a3 = dot2(w1[4*q+1], up(hv.y), a3);
            a0 = dot2(w0[4*q+2], up(hv.z), a0);  a2 = dot2(w1[4*q+2], up(hv.z), a2);
            a1 = dot2(w0[4*q+3], up(hv.w), a1);  a3 = dot2(w1[4*q+3], up(hv.w), a3);
        }
        // ---- LDS-resident pairs 100..127 ----
#pragma unroll
        for (int qq = 0; qq < QLD; ++qq) {
            const uint4 hv = hq[QRG + qq];
            const uint4 wv0 = wl4[(2 * qq)     * 512 + tid];
            const uint4 wv1 = wl4[(2 * qq + 1) * 512 + tid];
            a0 = dot2(up(wv0.x), up(hv.x), a0);  a2 = dot2(up(wv1.x), up(hv.x), a2);
            a1 = dot2(up(wv0.y), up(hv.y), a1);  a3 = dot2(up(wv1.y), up(hv.y), a3);
            a0 = dot2(up(wv0.z), up(hv.z), a0);  a2 = dot2(up(wv1.z), up(hv.z), a2);
            a1 = dot2(up(wv0.w), up(hv.w), a1);  a3 = dot2(up(wv1.w), up(hv.w), a3);
        }
        // my two gates (+ x-projection incl. biases)
        const f16x2 xg = up(xpc);
        const float gM0 = (a0 + a1) + (float)xg.x;   // e=0: i_u ; e=1: g_u
        const float gM1 = (a2 + a3) + (float)xg.y;   // e=0: f_u ; e=1: o_u
        // exchange with lane^1 (other gate pair of the same unit)
        const float p0 = __shfl_xor(gM0, 1);
        const float p1 = __shfl_xor(gM1, 1);
        const float gi = e ? p0 : gM0;
        const float gf = e ? p1 : gM1;
        const float gg = e ? gM0 : p0;
        const float go = e ? gM1 : p1;
        // LSTM cell (redundant in both lanes of the pair; deterministic)
        c_state = sigf(gf) * c_state + sigf(gi) * tanhfast(gg);
        const float hn = sigf(go) * tanhfast(c_state);

        _Float16* hw = h16 + ((t + 1) & 1) * 256;
        if (!e) hw[u] = (_Float16)hn;
        __syncthreads();                                             // h_t published
        if (tid < 32) Hd4[(size_t)t * 32 + tid] = ((const uint4*)hw)[tid];
        xpc = xpn;
    }
}

// ---------------- phase 3: decode ----------------
// out[b,t,o] = b_dec[o] + H[b,t,:256] . W_dec[o,:256]
__global__ void __attribute__((amdgpu_flat_work_group_size(256, 256)))
dec_kernel(const unsigned short* __restrict__ Hd_in,
           const float* __restrict__ W_dec, const float* __restrict__ b_dec,
           float* __restrict__ out)
{
    const unsigned short* Hd = Hd_in ? Hd_in : (const unsigned short*)(g_ntm_ws + XP_BYTES);
    __shared__ unsigned int wdl[64 * 132];    // W_dec pairs, padded stride 132
    __shared__ uint4 ht[32 * 32];             // 32 t-rows x 256 f16

    const int tid = threadIdx.x;
    const int b = blockIdx.x >> 2, q = blockIdx.x & 3;

    for (int idx = tid; idx < 64 * 128; idx += 256) {
        const int o = idx >> 7, pp = idx & 127;
        wdl[o * 132 + pp] = pack2f(W_dec[(size_t)o * 384 + 2 * pp],
                                   W_dec[(size_t)o * 384 + 2 * pp + 1]);
    }
    const int o = tid & 63, tq = tid >> 6;
    const float bd = b_dec[o];
    const uint4* Hdb  = (const uint4*)Hd + ((size_t)b * TT + (size_t)q * 128) * 32;
    float*       outb = out + ((size_t)b * TT + (size_t)q * 128) * 64;

    for (int s = 0; s < 4; ++s) {
        __syncthreads();
#pragma unroll
        for (int i = 0; i < 4; ++i) {
            const int idx = tid + 256 * i;                 // 1024 uint4 = 32 rows
            ht[idx] = Hdb[s * 1024 + idx];
        }
        __syncthreads();

        float acc[8];
#pragma unroll
        for (int j = 0; j < 8; ++j) acc[j] = 0.f;

#pragma unroll
        for (int c = 0; c < 8; ++c) {                      // k-chunks of 32 slices
            uint4 w0, w1, w2, w3;
            {
                const unsigned int* wp = wdl + o * 132 + 16 * c;
                w0 = make_uint4(wp[0],  wp[1],  wp[2],  wp[3]);
                w1 = make_uint4(wp[4],  wp[5],  wp[6],  wp[7]);
                w2 = make_uint4(wp[8],  wp[9],  wp[10], wp[11]);
                w3 = make_uint4(wp[12], wp[13], wp[14], wp[15]);
            }
#pragma unroll
            for (int j = 0; j < 8; ++j) {
                const uint4* hr = &ht[(tq * 8 + j) * 32 + 4 * c];
                const uint4 h0 = hr[0], h1 = hr[1], h2 = hr[2], h3 = hr[3];
                float d = acc[j];
                d = dot2(up(w0.x), up(h0.x), d); d = dot2(up(w0.y), up(h0.y), d);
                d = dot2(up(w0.z), up(h0.z), d); d = dot2(up(w0.w), up(h0.w), d);
                d = dot2(up(w1.x), up(h1.x), d); d = dot2(up(w1.y), up(h1.y), d);
                d = dot2(up(w1.z), up(h1.z), d); d = dot2(up(w1.w), up(h1.w), d);
                d = dot2(up(w2.x), up(h2.x), d); d = dot2(up(w2.y), up(h2.y), d);
                d = dot2(up(w2.z), up(h2.z), d); d = dot2(up(w2.w), up(h2.w), d);
                d = dot2(up(w3.x), up(h3.x), d); d = dot2(up(w3.y), up(h3.y), d);
                d = dot2(up(w3.z), up(h3.z), d); d = dot2(up(w3.w), up(h3.w), d);
                acc[j] = d;
            }
        }
#pragma unroll
        for (int j = 0; j < 8; ++j)
            outb[(size_t)(s * 32 + tq * 8 + j) * 64 + o] = acc[j] + bd;
    }
}

extern "C" void kernel_launch(void* const* d_in, const int* in_sizes, int n_in,
                              void* d_out, int out_size, void* d_ws, size_t ws_size,
                              hipStream_t stream) {
    const float* x_seq = (const float*)d_in[0];
    const float* W_ih  = (const float*)d_in[1];
    const float* W_hh  = (const float*)d_in[2];
    const float* b_ih  = (const float*)d_in[3];
    const float* b_hh  = (const float*)d_in[4];
    // d_in[5..8] unused: mem == 0 forever
    const float* W_dec = (const float*)d_in[9];
    const float* b_dec = (const float*)d_in[10];
    float* out = (float*)d_out;

    unsigned short* XPh = nullptr;   // null -> kernels fall back to g_ntm_ws
    unsigned short* Hd  = nullptr;
    if (ws_size >= (size_t)XP_BYTES + HD_BYTES) {
        XPh = (unsigned short*)d_ws;
        Hd  = (unsigned short*)((unsigned char*)d_ws + XP_BYTES);
    }

    hipLaunchKernelGGL(xproj_kernel, dim3(256), dim3(512), 0, stream,
                       x_seq, W_ih, b_ih, b_hh, XPh);

    const size_t smem_rec = (size_t)14 * 512 * 16 + 1024;   // 115712 B
    hipFuncSetAttribute((const void*)&ntm_rec,
                        hipFuncAttributeMaxDynamicSharedMemorySize, (int)smem_rec);
    hipLaunchKernelGGL(ntm_rec, dim3(NB), dim3(512), smem_rec, stream,
                       W_hh, XPh, Hd);

    hipLaunchKernelGGL(dec_kernel, dim3(256), dim3(256), 0, stream,
                       Hd, W_dec, b_dec, out);
}